// Round 6
// baseline (252.263 us; speedup 1.0000x reference)
//
#include <hip/hip_runtime.h>

#define HW    3136      // 56*56
#define HW4   784       // HW / 4
#define C_INN 256
#define C_SQZ 64
#define NB    32
#define NBC   (NB * C_INN)   // 8192 (b,c) pairs

typedef float f4 __attribute__((ext_vector_type(4)));

// ---------------------------------------------------------------------------
// Kernel 1: global average pool. One WAVE per (b,c) pair, 4 channels/block.
// No LDS, no syncthreads — pure wave shuffle reduce.
// ---------------------------------------------------------------------------
__global__ __launch_bounds__(256) void se_pool(const float* __restrict__ x,
                                               float* __restrict__ s) {
    const int wv   = threadIdx.x >> 6;
    const int lane = threadIdx.x & 63;
    const int bc   = blockIdx.x * 4 + wv;          // 2048 blocks * 4 waves = 8192
    const f4* xp = (const f4*)(x + (size_t)bc * HW);

    float acc = 0.0f;
    int i = lane;
    #pragma unroll
    for (int k = 0; k < 12; ++k, i += 64) {        // 12*64 = 768 float4s
        f4 v = xp[i];
        acc += (v.x + v.y) + (v.z + v.w);
    }
    if (i < HW4) {                                 // tail: lanes 0..15 (784-768)
        f4 v = xp[i];
        acc += (v.x + v.y) + (v.z + v.w);
    }
    #pragma unroll
    for (int off = 32; off; off >>= 1)
        acc += __shfl_down(acc, off, 64);
    if (lane == 0) s[bc] = acc * (1.0f / (float)HW);
}

// ---------------------------------------------------------------------------
// Kernel 2: tiny MLP 256 -> 64 -> 256 + hardsigmoid. One block per batch.
// All weight reads coalesced; wave-per-output shuffle reductions.
// ---------------------------------------------------------------------------
__global__ __launch_bounds__(256) void se_fc(const float* __restrict__ s,
                                             const float* __restrict__ w1,
                                             const float* __restrict__ b1,
                                             const float* __restrict__ w2,
                                             const float* __restrict__ b2,
                                             float* __restrict__ scale) {
    const int b    = blockIdx.x;        // 0..31
    const int wv   = threadIdx.x >> 6;  // 0..3
    const int lane = threadIdx.x & 63;
    __shared__ float tv[C_SQZ];

    // lane l holds s[b][4l .. 4l+3]
    const f4 sv = ((const f4*)(s + b * C_INN))[lane];

    // fc1: wave wv computes outputs o = wv*16 .. wv*16+15.
    // lane l loads w1[o][4l..4l+3] — 64 consecutive float4 = coalesced 1KB.
    const f4* w1v = (const f4*)w1;      // [64][64] of f4
    for (int k = 0; k < 16; ++k) {
        const int o = wv * 16 + k;
        f4 w = w1v[o * 64 + lane];
        float p = (w.x * sv.x + w.y * sv.y) + (w.z * sv.z + w.w * sv.w);
        #pragma unroll
        for (int off = 32; off; off >>= 1)
            p += __shfl_down(p, off, 64);
        if (lane == 0) tv[o] = p + b1[o];
    }
    __syncthreads();

    const float tvl = tv[lane];         // lane l caches tv[l]
    // fc2: wave wv computes outputs c = wv*64 .. wv*64+63.
    // lane l loads w2[c][l] — 64 consecutive floats = coalesced 256B.
    for (int j = 0; j < 64; ++j) {
        const int c = wv * 64 + j;
        float p = w2[c * C_SQZ + lane] * tvl;
        #pragma unroll
        for (int off = 32; off; off >>= 1)
            p += __shfl_down(p, off, 64);
        if (lane == 0) {
            // Hardsigmoid: clip(x+3, 0, 6) / 6
            float h = fminf(fmaxf(p + b2[c] + 3.0f, 0.0f), 6.0f) * (1.0f / 6.0f);
            scale[b * C_INN + c] = h;
        }
    }
}

// ---------------------------------------------------------------------------
// Kernel 3: excite. One block per (b,c) pair; block-uniform scale.
// Plain write-back stores: x (103MB) + out (103MB) both fit in 256MB L3,
// so stores can't evict the x lines the remaining reads need.
// ---------------------------------------------------------------------------
__global__ __launch_bounds__(256) void se_excite(const float* __restrict__ x,
                                                 const float* __restrict__ scale,
                                                 float* __restrict__ out) {
    const int bc = blockIdx.x;
    const float sc = scale[bc];
    const f4* xp = (const f4*)(x + (size_t)bc * HW);
    f4*       op = (f4*)(out + (size_t)bc * HW);
    for (int i = threadIdx.x; i < HW4; i += 256) {
        f4 v = xp[i];
        v.x *= sc; v.y *= sc; v.z *= sc; v.w *= sc;
        op[i] = v;
    }
}

// ---------------------------------------------------------------------------
extern "C" void kernel_launch(void* const* d_in, const int* in_sizes, int n_in,
                              void* d_out, int out_size, void* d_ws, size_t ws_size,
                              hipStream_t stream) {
    const float* x  = (const float*)d_in[0];
    const float* w1 = (const float*)d_in[1];
    const float* b1 = (const float*)d_in[2];
    const float* w2 = (const float*)d_in[3];
    const float* b2 = (const float*)d_in[4];
    float* out = (float*)d_out;

    float* s     = (float*)d_ws;            // [32*256] pooled means
    float* scale = (float*)d_ws + NBC;      // [32*256] excite scales

    se_pool<<<NBC / 4, 256, 0, stream>>>(x, s);
    se_fc<<<NB, 256, 0, stream>>>(s, w1, b1, w2, b2, scale);
    se_excite<<<NBC, 256, 0, stream>>>(x, scale, out);
}